// Round 17
// baseline (19.034 us; speedup 1.0000x reference)
//
#include <hip/hip_runtime.h>

// NeighborsConvolution: out[z,a,i] = sum_{b,x,j} [|r_b-r_a|<0.5] * (r_b-r_a)_x * W[x,i,j] * feat[z,b,j]
// B=8, N=1024, CIN=COUT=64.
//
// R17 vs R16 (work-phase split: ~4.4us VALU, ~2.5us LDS-pipe, ~2us idle):
//  - Geometry NEVER touches LDS: scan reads geom direct from global (12KB,
//    L1-resident, per-lane stride-12B). Deletes geo staging + its barrier +
//    48 ds_read_b32/wave.
//  - MERGED scan+walk single pass: ballot -> inline wave-uniform walk; the
//    hit lane's dx,dy,dz come via 3 readlanes of the scan's own registers
//    (bit-identical floats). Deletes masks array, second 16-step loop, and
//    3 uniform LDS reads per neighbor. Depth-2 feat pipeline kept
//    (consume = 3 FMAs; zero-overhead register shifts).
//  - LDS 60KB: wstage 48K (red0/red1 alias after pickup) + tmp[16][192] 12K.
//    R16 shell: 512 blocks x 1024 thr = 32 waves/CU cap. 3 barriers.
//  - Ascending-b consume order preserved -> absmax stays exactly 0.015625.

#define BATCHSZ 8
#define NPTS 1024
#define CIN 64
#define COUT 64
#define NXJ (3 * CIN)      // 192
#define NG (NXJ / 4)       // 48 float4 groups
#define WPB 16             // waves (points) per block
#define BS (WPB * 64)      // 1024 threads
#define GPW (NG / 8)       // 6 W-groups per wave (xj-split within 8-wave half)
#define NSTEP (NPTS / 64)  // 16 ballot steps

typedef float f32x2 __attribute__((ext_vector_type(2)));

// smem layout (floats), 15360 floats = 60KB:
//  [0,12288)     wstage 48KB -> after pickups: red0 @0, red1 @4096 (16KB each)
//  [12288,15360) tmp[16][192] (12KB)
#define SM_TMP 12288
#define SM_TOTAL 15360

__global__ __launch_bounds__(BS, 8) void neigh_conv_kernel(
    const float* __restrict__ feat,  // [B,N,CIN]
    const float* __restrict__ geom,  // [B,N,3]
    const float* __restrict__ W,     // [3,COUT,CIN]
    float* __restrict__ out)         // [B,N,COUT]
{
    const int lane = threadIdx.x & 63;
    const int wv   = threadIdx.x >> 6;    // 0..15
    const int h    = wv >> 3;             // half 0/1
    const int hw   = wv & 7;              // wave within half
    const int p    = blockIdx.x * WPB + wv;
    const int a    = p & (NPTS - 1);
    const int z    = p >> 10;              // uniform across block (16 | 1024)

    __shared__ __align__(16) float smem[SM_TOTAL];

    // ---- prologue: stage ALL of W (48KB, rotate-swizzled); 1 barrier ----
    {
        const float4* w4 = (const float4*)W;          // 3072 float4
        float4* ws = (float4*)smem;
        #pragma unroll
        for (int kk = 0; kk < 3; ++kk) {              // 3 independent loads
            const int k = threadIdx.x + kk * BS;
            // rotate swizzle: row i=k>>4, slot j4=k&15 -> (j4+i)&15
            const int idx = (k & ~15) | ((k + (k >> 4)) & 15);
            ws[idx] = w4[k];
        }
    }
    __syncthreads();   // B1: wstage visible

    // ---- W fragment pickup (rotated b128 reads; once per wave) ----
    const int g0 = hw * GPW;
    float4 wr[GPW];
    {
        const float4* ws = (const float4*)smem;
        #pragma unroll
        for (int q = 0; q < GPW; ++q) {
            const int g = g0 + q;
            const int x = g >> 4, c = g & 15;
            wr[q] = ws[x * 1024 + (lane << 4) + ((c + lane) & 15)];
        }
    }

    const float* gz = geom + (size_t)z * NPTS * 3;   // L1-resident (12KB)
    const float* fz = feat + (size_t)z * NPTS * CIN;
    const float gax = gz[a * 3 + 0];
    const float gay = gz[a * 3 + 1];
    const float gaz = gz[a * 3 + 2];

    // ---- merged scan + walk: ballot -> inline readlane-diff consume ----
    float acc0 = 0.f, acc1 = 0.f, acc2 = 0.f;
    // depth-2 pending pipeline: diffs + feat value (consume = 3 FMAs)
    float px1 = 0.f, py1 = 0.f, pz1 = 0.f, pf1 = 0.f;   // newest
    float px2 = 0.f, py2 = 0.f, pz2 = 0.f, pf2 = 0.f;   // oldest
    int   v1 = 0, v2 = 0;                                // valid flags (uniform)

    #pragma unroll
    for (int ss = 0; ss < NSTEP; ++ss) {
        const int b = ss * 64 + lane;
        float dx, dy, dz, d2;
        {
            // Bit-exact vs numpy near boundary: no contraction, left-assoc.
            #pragma clang fp contract(off)
            dx = gz[b * 3 + 0] - gax;    // global, per-lane stride 12B (L1)
            dy = gz[b * 3 + 1] - gay;
            dz = gz[b * 3 + 2] - gaz;
            d2 = dx * dx + dy * dy + dz * dz;
        }
        unsigned long long mm = __ballot(d2 < 0.25f);
        while (mm) {                     // wave-uniform scalar walk
            const int src = __ffsll(mm) - 1;
            mm &= mm - 1ull;
            const int bn = ss * 64 + src;
            // hit lane's scan diffs, bit-identical (no recompute, no LDS)
            const float nx = __int_as_float(__builtin_amdgcn_readlane(__float_as_int(dx), src));
            const float ny = __int_as_float(__builtin_amdgcn_readlane(__float_as_int(dy), src));
            const float nz = __int_as_float(__builtin_amdgcn_readlane(__float_as_int(dz), src));
            const float f = fz[(size_t)bn * CIN + lane];  // issue load NOW
            if (v2) {                    // consume oldest: 3 FMAs only
                acc0 = fmaf(px2, pf2, acc0);
                acc1 = fmaf(py2, pf2, acc1);
                acc2 = fmaf(pz2, pf2, acc2);
            }
            px2 = px1; py2 = py1; pz2 = pz1; pf2 = pf1; v2 = v1;
            px1 = nx;  py1 = ny;  pz1 = nz;  pf1 = f;   v1 = 1;
        }
    }
    if (v2) {                            // drain (ascending order preserved)
        acc0 = fmaf(px2, pf2, acc0);
        acc1 = fmaf(py2, pf2, acc1);
        acc2 = fmaf(pz2, pf2, acc2);
    }
    if (v1) {
        acc0 = fmaf(px1, pf1, acc0);
        acc1 = fmaf(py1, pf1, acc1);
        acc2 = fmaf(pz1, pf1, acc2);
    }

    float* tmp = smem + SM_TMP + wv * NXJ;
    tmp[0 * CIN + lane] = acc0;
    tmp[1 * CIN + lane] = acc1;
    tmp[2 * CIN + lane] = acc2;
    __syncthreads();   // B2: tmps visible; pickups long done -> red alias ok

    // ---- epilogue: per half, wave hw owns groups [6hw,6hw+6), 8 points ----
    float* red = smem + h * (8 * 8 * COUT);           // red0 @0, red1 @4096
    #pragma unroll
    for (int pp = 0; pp < 8; ++pp) {
        const float4* t4 = (const float4*)(smem + SM_TMP + (h * 8 + pp) * NXJ);
        f32x2 facc = {0.f, 0.f};
        #pragma unroll
        for (int q = 0; q < GPW; ++q) {
            const float4 t = t4[g0 + q];          // uniform -> LDS broadcast
            f32x2 ta; ta.x = t.x; ta.y = t.y;
            f32x2 tb; tb.x = t.z; tb.y = t.w;
            f32x2 wa; wa.x = wr[q].x; wa.y = wr[q].y;
            f32x2 wb; wb.x = wr[q].z; wb.y = wr[q].w;
            facc = ta * wa + facc;                // v_pk_fma_f32
            facc = tb * wb + facc;
        }
        red[(hw * 8 + pp) * COUT + lane] = facc.x + facc.y;
    }
    __syncthreads();   // B3

    // ---- reduce within half + store ----
    float o = 0.f;
    #pragma unroll
    for (int w = 0; w < 8; ++w)
        o += red[(w * 8 + hw) * COUT + lane];     // 2 lanes/bank: free

    out[(size_t)p * COUT + lane] = o;
}

extern "C" void kernel_launch(void* const* d_in, const int* in_sizes, int n_in,
                              void* d_out, int out_size, void* d_ws, size_t ws_size,
                              hipStream_t stream) {
    const float* feat = (const float*)d_in[0];  // [8,1024,64]
    const float* geom = (const float*)d_in[1];  // [8,1024,3]
    const float* W    = (const float*)d_in[2];  // [3,64,64]
    float* out        = (float*)d_out;          // [8,1024,64]

    const int nblocks = BATCHSZ * NPTS / WPB;   // 512 blocks x 1024 threads
    neigh_conv_kernel<<<nblocks, BS, 0, stream>>>(feat, geom, W, out);
}